// Round 10
// baseline (163.930 us; speedup 1.0000x reference)
//
#include <hip/hip_runtime.h>

#define EPS 1e-5f
constexpr float INV_N1 = 1.f / 524288.f;   // D*U*2
constexpr float INV_N3 = 1.f / 262144.f;   // D*U

__device__ __forceinline__ float lrelu(float y) { return fmaxf(y, 0.01f * y); }

template <int CTRL>
__device__ __forceinline__ float dppMov(float v) {
    return __int_as_float(__builtin_amdgcn_update_dpp(
        0, __float_as_int(v), CTRL, 0xF, 0xF, true));
}
// sum within each 16-lane row; valid at lane%16==15
__device__ __forceinline__ float rowSumDpp(float v) {
    v += dppMov<0x111>(v);
    v += dppMov<0x112>(v);
    v += dppMov<0x114>(v);
    v += dppMov<0x118>(v);
    return v;
}
// sum over each 4-lane quad (all quad lanes get it)
__device__ __forceinline__ float quadSum(float v) {
    v += dppMov<0xB1>(v);
    v += dppMov<0x4E>(v);
    return v;
}
__device__ __forceinline__ float waveAllSum(float v) {
    v += __shfl_xor(v, 32); v += __shfl_xor(v, 16); v += __shfl_xor(v, 8);
    v += __shfl_xor(v, 4);  v += __shfl_xor(v, 2);  v += __shfl_xor(v, 1);
    return v;
}

// ---------------------------------------------------------------------------
// kA: 640 blocks.
//  [0,512):   per-d sums of w1/b1 -> S4 = (S1,S2,S11,S0b), Sb2
//  [512,576): partial column sums of g3/be3 -> Gp/Bp
//  [576,640): LN0 per batch -> xn, xnT, Xs
//  LAST block (counter): fold Gp/Bp -> G3s/Be3s; LN1 stats -> rs1a/mm1a.
// ---------------------------------------------------------------------------
__global__ void __launch_bounds__(256) kA(
    const float* __restrict__ w1, const float* __restrict__ b1,
    const float* __restrict__ g3, const float* __restrict__ be3,
    const float* __restrict__ x, const float* __restrict__ g0,
    const float* __restrict__ be0,
    float4* __restrict__ S4, float* __restrict__ Sb2,
    float* __restrict__ Gp, float* __restrict__ Bp,
    float* __restrict__ xnp, float* __restrict__ xnT, float* __restrict__ Xs,
    float* __restrict__ rs1a, float* __restrict__ mm1a,
    float* __restrict__ G3s, float* __restrict__ Be3s,
    unsigned int* __restrict__ ctr) {
    int bid = blockIdx.x, tid = threadIdx.x;
    int wave = tid >> 6, lane = tid & 63;
    __shared__ float red[4][5];
    __shared__ float bc[2];
    __shared__ int sflag;
    if (bid < 512) {
        const float4* wr = (const float4*)(w1 + bid * 1024);
        const float4* br = (const float4*)(b1 + bid * 1024);
        float4 w = wr[tid], b = br[tid];
        float s1  = w.x + w.y + w.z + w.w;
        float s2  = w.x * w.x + w.y * w.y + w.z * w.z + w.w * w.w;
        float s11 = w.x * b.x + w.y * b.y + w.z * b.z + w.w * b.w;
        float s0  = b.x + b.y + b.z + b.w;
        float sb2 = b.x * b.x + b.y * b.y + b.z * b.z + b.w * b.w;
        s1 = waveAllSum(s1); s2 = waveAllSum(s2); s11 = waveAllSum(s11);
        s0 = waveAllSum(s0); sb2 = waveAllSum(sb2);
        if (lane == 0) {
            red[wave][0] = s1; red[wave][1] = s2; red[wave][2] = s11;
            red[wave][3] = s0; red[wave][4] = sb2;
        }
        __syncthreads();
        if (tid == 0) {
            float a0 = 0, a1 = 0, a2 = 0, a3 = 0, a4 = 0;
            for (int w4 = 0; w4 < 4; ++w4) {
                a0 += red[w4][0]; a1 += red[w4][1]; a2 += red[w4][2];
                a3 += red[w4][3]; a4 += red[w4][4];
            }
            S4[bid] = make_float4(a0, a1, a2, a3);
            Sb2[bid] = a4;
        }
    } else if (bid < 576) {
        int jj = bid - 512;
        float ag0 = 0, ag1 = 0, ab0 = 0, ab1 = 0;
#pragma unroll
        for (int r = 0; r < 8; ++r) {
            const float* gr = g3 + (jj * 8 + r) * 512;
            const float* br = be3 + (jj * 8 + r) * 512;
            ag0 += gr[tid];  ag1 += gr[tid + 256];
            ab0 += br[tid];  ab1 += br[tid + 256];
        }
        Gp[jj * 512 + tid] = ag0; Gp[jj * 512 + tid + 256] = ag1;
        Bp[jj * 512 + tid] = ab0; Bp[jj * 512 + tid + 256] = ab1;
    } else {
        int b = bid - 576;
        float2 xv = ((const float2*)(x + b * 512))[tid];
        float sx = xv.x + xv.y, sxx = xv.x * xv.x + xv.y * xv.y;
        sx = waveAllSum(sx); sxx = waveAllSum(sxx);
        if (lane == 0) { red[wave][0] = sx; red[wave][1] = sxx; }
        __syncthreads();
        if (tid == 0) {
            float s = red[0][0] + red[1][0] + red[2][0] + red[3][0];
            float c = red[0][1] + red[1][1] + red[2][1] + red[3][1];
            float m = s * (1.f / 512.f);
            float var = c * (1.f / 512.f) - m * m;
            bc[0] = m; bc[1] = rsqrtf(var + EPS);
        }
        __syncthreads();
        float m = bc[0], rsd = bc[1];
        float2 g = ((const float2*)g0)[tid], be = ((const float2*)be0)[tid];
        float xn0 = (xv.x - m) * rsd * g.x + be.x;
        float xn1 = (xv.y - m) * rsd * g.y + be.y;
        ((float2*)(xnp + b * 512))[tid] = make_float2(xn0, xn1);
        xnT[(2 * tid) * 64 + b] = xn0;
        xnT[(2 * tid + 1) * 64 + b] = xn1;
        float sxn = waveAllSum(xn0 + xn1);
        __syncthreads();
        if (lane == 0) red[wave][0] = sxn;
        __syncthreads();
        if (tid == 0) Xs[b] = red[0][0] + red[1][0] + red[2][0] + red[3][0];
    }
    // ---- last-block tail ----
    __syncthreads();
    if (tid == 0) {
        __threadfence();
        unsigned int old = atomicAdd(ctr, 1u);
        sflag = (old == 639u);
    }
    __syncthreads();
    if (sflag) {
        __threadfence();   // acquire: invalidate caches before reading peers' data
        __shared__ float pmW[4][64], peW[4][64];
        __shared__ float cW[4][2];
        {
            int b = lane;
            float pm = 0, pe = 0, c0 = 0, cb = 0;
            for (int i = 0; i < 128; ++i) {
                int dd = wave * 128 + i;
                float4 sv = S4[dd];
                float xd = xnT[dd * 64 + b];
                pm = fmaf(xd, sv.x, pm);
                pe += xd * xd * sv.y + 2.f * xd * sv.z;
                c0 += sv.w; cb += Sb2[dd];
            }
            pmW[wave][b] = pm; peW[wave][b] = pe;
            if (lane == 0) { cW[wave][0] = c0; cW[wave][1] = cb; }
        }
        __syncthreads();
        if (tid < 64) {
            float c0t = cW[0][0] + cW[1][0] + cW[2][0] + cW[3][0];
            float cbt = cW[0][1] + cW[1][1] + cW[2][1] + cW[3][1];
            float pm = pmW[0][tid] + pmW[1][tid] + pmW[2][tid] + pmW[3][tid] + c0t;
            float pe = peW[0][tid] + peW[1][tid] + peW[2][tid] + peW[3][tid] + cbt;
            float m1 = pm * INV_N1, e1 = pe * INV_N1;
            float r = rsqrtf(e1 - m1 * m1 + EPS);
            rs1a[tid] = r; mm1a[tid] = m1 * r;
        }
        for (int uu = tid; uu < 512; uu += 256) {
            float g = 0, bb = 0;
#pragma unroll 8
            for (int jj = 0; jj < 64; ++jj) {
                g  += Gp[jj * 512 + uu];
                bb += Bp[jj * 512 + uu];
            }
            G3s[uu] = g; Be3s[uu] = bb;
        }
    }
}

// ---------------------------------------------------------------------------
// k1: 512 blocks x 512 threads (d = bid, u = tid). Pure main loop (no
// prologue). Zeroes ppA/qpA slice for k2's atomics. Conflict-free red2k,
// coalesced store part1[bid][128] (slot = k*64+b).
// ---------------------------------------------------------------------------
__global__ void __launch_bounds__(512) k1(
    const float* __restrict__ w1, const float* __restrict__ b1,
    const float* __restrict__ g1, const float* __restrict__ be1,
    const float* __restrict__ w21, const float* __restrict__ w22,
    const float* __restrict__ b21, const float* __restrict__ b22,
    const float* __restrict__ xnT, const float* __restrict__ rs1a,
    const float* __restrict__ mm1a,
    float* __restrict__ part1, float* __restrict__ zeroReg) {
    int bid = blockIdx.x, tid = threadIdx.x;
    int d = bid;
    int wave = tid >> 6, lane = tid & 63;
    // zero ppA/qpA slice (34816 floats total / 512 blocks = 68 each)
    if (tid < 68) {
        int idx = bid * 68 + tid;
        if (idx < 34816) zeroReg[idx] = 0.f;
    }
    __shared__ float xcol[64], scA[64], scB[64];
    __shared__ float red2k[2][32][72];
    if (tid < 64) {
        xcol[tid] = xnT[d * 64 + tid];
        scA[tid] = rs1a[tid];
        scB[tid] = mm1a[tid];
    }
    int i0 = d * 512 + tid;
    float2 W1 = ((const float2*)w1)[i0], B1 = ((const float2*)b1)[i0];
    float2 G1 = ((const float2*)g1)[i0], E1 = ((const float2*)be1)[i0];
    float2 A  = ((const float2*)w21)[i0], C = ((const float2*)w22)[i0];
    float Ba = b21[i0], Bc = b22[i0];
    __syncthreads();
    for (int b = 0; b < 64; ++b) {
        float xd = xcol[b], r1 = scA[b], mmv = scB[b];
        float t0 = fmaf(xd, W1.x, B1.x), t1 = fmaf(xd, W1.y, B1.y);
        float z0 = fmaf(t0, r1, -mmv), z1 = fmaf(t1, r1, -mmv);
        float y0 = fmaf(z0, G1.x, E1.x), y1 = fmaf(z1, G1.y, E1.y);
        float l0 = lrelu(y0), l1 = lrelu(y1);
        float c0 = fmaf(l0, A.x, fmaf(l1, A.y, Ba));
        float c1 = fmaf(l0, C.x, fmaf(l1, C.y, Bc));
        float v1 = c0 + c1;
        float v2 = fmaf(c0, c0, c1 * c1);
        v1 = rowSumDpp(v1);
        v2 = rowSumDpp(v2);
        if ((lane & 15) == 15) {
            int slot = wave * 4 + (lane >> 4);
            red2k[0][slot][b] = v1;
            red2k[1][slot][b] = v2;
        }
    }
    __syncthreads();
    if (tid < 128) {   // s = k*64 + b
        int k = tid >> 6, b2 = tid & 63;
        float s = 0;
#pragma unroll
        for (int slot = 0; slot < 32; ++slot) s += red2k[k][slot][b2];
        part1[bid * 128 + tid] = s;
    }
}

// ---------------------------------------------------------------------------
// k2: 512 blocks (bd 16 x bu 32) x 256. Prologue: fold part1 -> LN2 stats.
// Main: 2 d's/thread, quadSum, lane-private LDS accumulators. Epilogue:
// atomic p into ppA[64][512]; atomic q/q2 into padded qpA. LAST block: k3
// (LN3 stats + finalize output).
// ---------------------------------------------------------------------------
struct Wt { float2 W1, B1, G1, E1, A, C, G2, E2, W3; float Ba, Bc, B3, G3v; };

__global__ void __launch_bounds__(256) k2(
    const float* __restrict__ w1, const float* __restrict__ b1,
    const float* __restrict__ g1, const float* __restrict__ be1,
    const float* __restrict__ w21, const float* __restrict__ w22,
    const float* __restrict__ b21, const float* __restrict__ b22,
    const float* __restrict__ g2, const float* __restrict__ be2,
    const float* __restrict__ w3, const float* __restrict__ b3,
    const float* __restrict__ g3,
    const float* __restrict__ xnp, const float* __restrict__ rs1a,
    const float* __restrict__ mm1a, const float* __restrict__ part1,
    float* __restrict__ ppA, float* __restrict__ qpA,
    const float* __restrict__ G3s, const float* __restrict__ Be3s,
    const float* __restrict__ Xs, const float* __restrict__ bias,
    float* __restrict__ out, unsigned int* __restrict__ ctr) {
    int bu = blockIdx.x & 31, bd = blockIdx.x >> 5, tid = threadIdx.x;
    int lane = tid & 63, wave = tid >> 6;
    int ul = (lane >> 2) & 15, d0 = lane & 3;
    int u = bu * 16 + ul;
    int dl0 = wave * 8 + d0 * 2;
    __shared__ float4 sc[64];
    __shared__ float sxn[64][32];
    __shared__ float comb[4][64][16][3];
    __shared__ float tmp2[2][128];
    __shared__ int sflag;
    {
        int s = tid & 127, half = tid >> 7;
        float acc = 0;
        const float* p = part1 + half * 256 * 128 + s;
#pragma unroll 8
        for (int blk = 0; blk < 256; ++blk) acc += p[blk * 128];
        tmp2[half][s] = acc;
    }
    {
        float* cz = &comb[0][0][0][0];
        for (int t = tid; t < 4 * 64 * 16 * 3; t += 256) cz[t] = 0.f;
    }
    for (int idx = tid; idx < 2048; idx += 256)
        sxn[idx >> 5][idx & 31] = xnp[(idx >> 5) * 512 + bd * 32 + (idx & 31)];
    Wt wt[2];
#pragma unroll
    for (int j = 0; j < 2; ++j) {
        int d = bd * 32 + dl0 + j;
        int i = d * 512 + u;
        wt[j].W1 = ((const float2*)w1)[i];  wt[j].B1 = ((const float2*)b1)[i];
        wt[j].G1 = ((const float2*)g1)[i];  wt[j].E1 = ((const float2*)be1)[i];
        wt[j].A  = ((const float2*)w21)[i]; wt[j].C  = ((const float2*)w22)[i];
        wt[j].G2 = ((const float2*)g2)[i];  wt[j].E2 = ((const float2*)be2)[i];
        wt[j].W3 = ((const float2*)w3)[i];
        wt[j].Ba = b21[i]; wt[j].Bc = b22[i]; wt[j].B3 = b3[i]; wt[j].G3v = g3[i];
    }
    __syncthreads();
    if (tid < 64) {
        float ssum  = tmp2[0][tid] + tmp2[1][tid];
        float s2sum = tmp2[0][64 + tid] + tmp2[1][64 + tid];
        float mm = ssum * INV_N1;
        float var = s2sum * INV_N1 - mm * mm;
        float r2 = rsqrtf(var + EPS);
        sc[tid] = make_float4(rs1a[tid], mm1a[tid], r2, mm * r2);
    }
    __syncthreads();
    for (int b = 0; b < 64; ++b) {
        float4 s4 = sc[b];
        float p = 0, q = 0, q2 = 0;
#pragma unroll
        for (int j = 0; j < 2; ++j) {
            float xd = sxn[b][dl0 + j];
            float t0 = fmaf(xd, wt[j].W1.x, wt[j].B1.x), t1 = fmaf(xd, wt[j].W1.y, wt[j].B1.y);
            float z0 = fmaf(t0, s4.x, -s4.y), z1 = fmaf(t1, s4.x, -s4.y);
            float y0 = fmaf(z0, wt[j].G1.x, wt[j].E1.x), y1 = fmaf(z1, wt[j].G1.y, wt[j].E1.y);
            float l0 = lrelu(y0), l1 = lrelu(y1);
            float c0 = fmaf(l0, wt[j].A.x, fmaf(l1, wt[j].A.y, wt[j].Ba));
            float c1 = fmaf(l0, wt[j].C.x, fmaf(l1, wt[j].C.y, wt[j].Bc));
            float z20 = fmaf(c0, s4.z, -s4.w), z21 = fmaf(c1, s4.z, -s4.w);
            float y20 = fmaf(z20, wt[j].G2.x, wt[j].E2.x), y21 = fmaf(z21, wt[j].G2.y, wt[j].E2.y);
            float m0 = lrelu(y20), m1v = lrelu(y21);
            float l3 = fmaf(m0, wt[j].W3.x, fmaf(m1v, wt[j].W3.y, wt[j].B3));
            p = fmaf(l3, wt[j].G3v, p); q += l3; q2 = fmaf(l3, l3, q2);
        }
        p = quadSum(p); q = quadSum(q); q2 = quadSum(q2);
        if (d0 < 3) {
            float v = (d0 == 0) ? p : ((d0 == 1) ? q : q2);
            comb[wave][b][ul][d0] += v;
        }
    }
    __syncthreads();
#pragma unroll
    for (int r = 0; r < 4; ++r) {
        int idx = r * 256 + tid;
        int b = idx >> 4, uu = idx & 15;
        float s = comb[0][b][uu][0] + comb[1][b][uu][0]
                + comb[2][b][uu][0] + comb[3][b][uu][0];
        unsafeAtomicAdd(&ppA[b * 512 + bu * 16 + uu], s);
    }
    if (tid < 128) {   // tid = b*2+k
        int b = tid >> 1, st = 1 + (tid & 1);
        float s = 0;
#pragma unroll
        for (int w = 0; w < 4; ++w)
#pragma unroll
            for (int uu = 0; uu < 16; ++uu) s += comb[w][b][uu][st];
        unsafeAtomicAdd(&qpA[tid * 16], s);
    }
    // ---- last-block tail: k3 ----
    __syncthreads();
    if (tid == 0) {
        __threadfence();
        unsigned int old = atomicAdd(ctr, 1u);
        sflag = (old == 511u);
    }
    __syncthreads();
    if (sflag) {
        __threadfence();
        __shared__ float m3s[64], rs3s[64], xsb[64];
        if (tid < 64) {
            float q  = qpA[(2 * tid) * 16];
            float q2 = qpA[(2 * tid + 1) * 16];
            float m3 = q * INV_N3, e3 = q2 * INV_N3;
            m3s[tid] = m3;
            rs3s[tid] = rsqrtf(e3 - m3 * m3 + EPS);
            xsb[tid] = Xs[tid];
        }
        __syncthreads();
        for (int idx = tid; idx < 32768; idx += 256) {
            int b = idx >> 9, uu = idx & 511;
            float val = rs3s[b] * (ppA[idx] - m3s[b] * G3s[uu])
                      + Be3s[uu] + xsb[b] + bias[uu];
            out[idx] = lrelu(val);
        }
    }
}

extern "C" void kernel_launch(void* const* d_in, const int* in_sizes, int n_in,
                              void* d_out, int out_size, void* d_ws, size_t ws_size,
                              hipStream_t stream) {
    const float* x   = (const float*)d_in[0];
    const float* w1  = (const float*)d_in[1];
    const float* b1  = (const float*)d_in[2];
    const float* w21 = (const float*)d_in[3];
    const float* w22 = (const float*)d_in[4];
    const float* b21 = (const float*)d_in[5];
    const float* b22 = (const float*)d_in[6];
    const float* w3  = (const float*)d_in[7];
    const float* b3  = (const float*)d_in[8];
    const float* bias= (const float*)d_in[9];
    const float* g0  = (const float*)d_in[10];
    const float* be0 = (const float*)d_in[11];
    const float* g1  = (const float*)d_in[12];
    const float* be1 = (const float*)d_in[13];
    const float* g2  = (const float*)d_in[14];
    const float* be2 = (const float*)d_in[15];
    const float* g3  = (const float*)d_in[16];
    const float* be3 = (const float*)d_in[17];
    float* out = (float*)d_out;
    char* ws = (char*)d_ws;

    unsigned int* ctr0 = (unsigned int*)ws;            // 4 B
    unsigned int* ctr1 = (unsigned int*)(ws + 64);     // 4 B
    float*  xn    = (float*)(ws + 256);                // 131072 [B][D]
    float*  xnT   = (float*)(ws + 131328);             // 131072 [D][B]
    float4* S4    = (float4*)(ws + 262400);            // 8192
    float*  Sb2   = (float*)(ws + 270592);             // 2048
    float*  rs1a  = (float*)(ws + 272640);             // 256
    float*  mm1a  = (float*)(ws + 272896);             // 256
    float*  Xs    = (float*)(ws + 273152);             // 256
    float*  G3s   = (float*)(ws + 273408);             // 2048
    float*  Be3s  = (float*)(ws + 275456);             // 2048
    float*  Gp    = (float*)(ws + 277504);             // 131072 [64][512]
    float*  Bp    = (float*)(ws + 408576);             // 131072
    float*  part1 = (float*)(ws + 539648);             // 262144 [512][128]
    float*  ppA   = (float*)(ws + 801792);             // 131072 [64][512]
    float*  qpA   = (float*)(ws + 932864);             // 8192   [128]x16

    hipMemsetAsync(ws, 0, 128, stream);   // zero the two counters
    hipLaunchKernelGGL(kA, dim3(640), dim3(256), 0, stream,
                       w1, b1, g3, be3, x, g0, be0,
                       S4, Sb2, Gp, Bp, xn, xnT, Xs,
                       rs1a, mm1a, G3s, Be3s, ctr0);
    hipLaunchKernelGGL(k1, dim3(512), dim3(512), 0, stream,
                       w1, b1, g1, be1, w21, w22, b21, b22,
                       xnT, rs1a, mm1a, part1, ppA);
    hipLaunchKernelGGL(k2, dim3(512), dim3(256), 0, stream,
                       w1, b1, g1, be1, w21, w22, b21, b22, g2, be2, w3, b3, g3,
                       xn, rs1a, mm1a, part1, ppA, qpA,
                       G3s, Be3s, Xs, bias, out, ctr1);
}

// Round 11
// 124.710 us; speedup vs baseline: 1.3145x; 1.3145x over previous
//
#include <hip/hip_runtime.h>

#define EPS 1e-5f
constexpr float INV_N1 = 1.f / 524288.f;   // D*U*2
constexpr float INV_N3 = 1.f / 262144.f;   // D*U

__device__ __forceinline__ float lrelu(float y) { return fmaxf(y, 0.01f * y); }

__device__ __forceinline__ float waveAllSum(float v) {
    v += __shfl_xor(v, 32); v += __shfl_xor(v, 16); v += __shfl_xor(v, 8);
    v += __shfl_xor(v, 4);  v += __shfl_xor(v, 2);  v += __shfl_xor(v, 1);
    return v;
}

// ---------------------------------------------------------------------------
// kA: 640 blocks.
//  [0,512):   per-d sums of w1/b1 -> S4=(S1,S2,S11,S0b), Sb2
//  [512,576): partial column sums of g3/be3 -> Gp/Bp
//  [576,640): LN0 per batch -> xn, xnT (transposed), Xs
// ---------------------------------------------------------------------------
__global__ void __launch_bounds__(256) kA(
    const float* __restrict__ w1, const float* __restrict__ b1,
    const float* __restrict__ g3, const float* __restrict__ be3,
    const float* __restrict__ x, const float* __restrict__ g0,
    const float* __restrict__ be0,
    float4* __restrict__ S4, float* __restrict__ Sb2,
    float* __restrict__ Gp, float* __restrict__ Bp,
    float* __restrict__ xnp, float* __restrict__ xnT, float* __restrict__ Xs) {
    int bid = blockIdx.x, tid = threadIdx.x;
    int wave = tid >> 6, lane = tid & 63;
    __shared__ float red[4][5];
    __shared__ float bc[2];
    if (bid < 512) {
        const float4* wr = (const float4*)(w1 + bid * 1024);
        const float4* br = (const float4*)(b1 + bid * 1024);
        float4 w = wr[tid], b = br[tid];
        float s1  = w.x + w.y + w.z + w.w;
        float s2  = w.x * w.x + w.y * w.y + w.z * w.z + w.w * w.w;
        float s11 = w.x * b.x + w.y * b.y + w.z * b.z + w.w * b.w;
        float s0  = b.x + b.y + b.z + b.w;
        float sb2 = b.x * b.x + b.y * b.y + b.z * b.z + b.w * b.w;
        s1 = waveAllSum(s1); s2 = waveAllSum(s2); s11 = waveAllSum(s11);
        s0 = waveAllSum(s0); sb2 = waveAllSum(sb2);
        if (lane == 0) {
            red[wave][0] = s1; red[wave][1] = s2; red[wave][2] = s11;
            red[wave][3] = s0; red[wave][4] = sb2;
        }
        __syncthreads();
        if (tid == 0) {
            float a0 = 0, a1 = 0, a2 = 0, a3 = 0, a4 = 0;
            for (int w4 = 0; w4 < 4; ++w4) {
                a0 += red[w4][0]; a1 += red[w4][1]; a2 += red[w4][2];
                a3 += red[w4][3]; a4 += red[w4][4];
            }
            S4[bid] = make_float4(a0, a1, a2, a3);
            Sb2[bid] = a4;
        }
    } else if (bid < 576) {
        int jj = bid - 512;
        float ag0 = 0, ag1 = 0, ab0 = 0, ab1 = 0;
#pragma unroll
        for (int r = 0; r < 8; ++r) {
            const float* gr = g3 + (jj * 8 + r) * 512;
            const float* br = be3 + (jj * 8 + r) * 512;
            ag0 += gr[tid];  ag1 += gr[tid + 256];
            ab0 += br[tid];  ab1 += br[tid + 256];
        }
        Gp[jj * 512 + tid] = ag0; Gp[jj * 512 + tid + 256] = ag1;
        Bp[jj * 512 + tid] = ab0; Bp[jj * 512 + tid + 256] = ab1;
    } else {
        int b = bid - 576;
        float2 xv = ((const float2*)(x + b * 512))[tid];
        float sx = xv.x + xv.y, sxx = xv.x * xv.x + xv.y * xv.y;
        sx = waveAllSum(sx); sxx = waveAllSum(sxx);
        if (lane == 0) { red[wave][0] = sx; red[wave][1] = sxx; }
        __syncthreads();
        if (tid == 0) {
            float s = red[0][0] + red[1][0] + red[2][0] + red[3][0];
            float c = red[0][1] + red[1][1] + red[2][1] + red[3][1];
            float m = s * (1.f / 512.f);
            float var = c * (1.f / 512.f) - m * m;
            bc[0] = m; bc[1] = rsqrtf(var + EPS);
        }
        __syncthreads();
        float m = bc[0], rsd = bc[1];
        float2 g = ((const float2*)g0)[tid], be = ((const float2*)be0)[tid];
        float xn0 = (xv.x - m) * rsd * g.x + be.x;
        float xn1 = (xv.y - m) * rsd * g.y + be.y;
        ((float2*)(xnp + b * 512))[tid] = make_float2(xn0, xn1);
        xnT[(2 * tid) * 64 + b] = xn0;
        xnT[(2 * tid + 1) * 64 + b] = xn1;
        float sxn = waveAllSum(xn0 + xn1);
        __syncthreads();
        if (lane == 0) red[wave][0] = sxn;
        __syncthreads();
        if (tid == 0) Xs[b] = red[0][0] + red[1][0] + red[2][0] + red[3][0];
    }
}

// ---------------------------------------------------------------------------
// kB: 66 blocks. [0,64): analytic LN1 stats per batch from S4/Sb2 + xn.
//     [64]: fold Gp -> G3s. [65]: fold Bp -> Be3s.
// ---------------------------------------------------------------------------
__global__ void __launch_bounds__(256) kB(
    const float* __restrict__ xn, const float4* __restrict__ S4,
    const float* __restrict__ Sb2,
    const float* __restrict__ Gp, const float* __restrict__ Bp,
    float* __restrict__ rs1a, float* __restrict__ mm1a,
    float* __restrict__ G3s, float* __restrict__ Be3s) {
    int bid = blockIdx.x, tid = threadIdx.x;
    if (bid < 64) {
        int b = bid;
        __shared__ float red[4][2];
        float2 xv = ((const float2*)(xn + b * 512))[tid];
        float4 sa = S4[2 * tid], sb = S4[2 * tid + 1];
        float pm = fmaf(xv.x, sa.x, sa.w) + fmaf(xv.y, sb.x, sb.w);
        float pe = xv.x * xv.x * sa.y + 2.f * xv.x * sa.z + Sb2[2 * tid]
                 + xv.y * xv.y * sb.y + 2.f * xv.y * sb.z + Sb2[2 * tid + 1];
        pm = waveAllSum(pm); pe = waveAllSum(pe);
        int wave = tid >> 6, lane = tid & 63;
        if (lane == 0) { red[wave][0] = pm; red[wave][1] = pe; }
        __syncthreads();
        if (tid == 0) {
            float s = red[0][0] + red[1][0] + red[2][0] + red[3][0];
            float c = red[0][1] + red[1][1] + red[2][1] + red[3][1];
            float m1 = s * INV_N1, e1 = c * INV_N1;
            float r = rsqrtf(e1 - m1 * m1 + EPS);
            rs1a[b] = r; mm1a[b] = m1 * r;
        }
    } else if (bid == 64) {
        for (int u = tid; u < 512; u += 256) {
            float s = 0;
#pragma unroll 8
            for (int jj = 0; jj < 64; ++jj) s += Gp[jj * 512 + u];
            G3s[u] = s;
        }
    } else {
        for (int u = tid; u < 512; u += 256) {
            float s = 0;
#pragma unroll 8
            for (int jj = 0; jj < 64; ++jj) s += Bp[jj * 512 + u];
            Be3s[u] = s;
        }
    }
}

// ---------------------------------------------------------------------------
// k1: LN2 stat partials. 512 blocks (d=bid) x 256. LANE = BATCH layout:
// per-lane accumulators in registers, wave-uniform (scalar) weight loads,
// no reductions/LDS/barriers in the loop. One end fold -> part1[d][128].
// ---------------------------------------------------------------------------
__global__ void __launch_bounds__(256) k1(
    const float* __restrict__ w1, const float* __restrict__ b1,
    const float* __restrict__ g1, const float* __restrict__ be1,
    const float* __restrict__ w21, const float* __restrict__ w22,
    const float* __restrict__ b21, const float* __restrict__ b22,
    const float* __restrict__ xnT, const float* __restrict__ rs1a,
    const float* __restrict__ mm1a, float* __restrict__ part1) {
    int d = blockIdx.x, tid = threadIdx.x;
    int lane = tid & 63;
    int wv = __builtin_amdgcn_readfirstlane(tid >> 6);   // wave-uniform
    float xd = xnT[d * 64 + lane];
    float r1 = rs1a[lane], mm = mm1a[lane];
    float v1 = 0.f, v2 = 0.f;
    int base = d * 512 + wv * 128;
#pragma unroll 4
    for (int i = 0; i < 128; ++i) {
        int idx = base + i;
        float2 W1 = ((const float2*)w1)[idx], B1 = ((const float2*)b1)[idx];
        float2 G1 = ((const float2*)g1)[idx], E1 = ((const float2*)be1)[idx];
        float2 A  = ((const float2*)w21)[idx], C = ((const float2*)w22)[idx];
        float Ba = b21[idx], Bc = b22[idx];
        float t0 = fmaf(xd, W1.x, B1.x), t1 = fmaf(xd, W1.y, B1.y);
        float z0 = fmaf(t0, r1, -mm),   z1 = fmaf(t1, r1, -mm);
        float y0 = fmaf(z0, G1.x, E1.x), y1 = fmaf(z1, G1.y, E1.y);
        float l0 = lrelu(y0), l1 = lrelu(y1);
        float c0 = fmaf(l0, A.x, fmaf(l1, A.y, Ba));
        float c1 = fmaf(l0, C.x, fmaf(l1, C.y, Bc));
        v1 += c0 + c1;
        v2 = fmaf(c0, c0, fmaf(c1, c1, v2));
    }
    __shared__ float vacc[4][64][2];
    vacc[wv][lane][0] = v1;
    vacc[wv][lane][1] = v2;
    __syncthreads();
    if (tid < 128) {   // slot s = k*64 + b
        int k = tid >> 6, b = tid & 63;
        float s = vacc[0][b][k] + vacc[1][b][k] + vacc[2][b][k] + vacc[3][b][k];
        part1[d * 128 + tid] = s;
    }
}

// ---------------------------------------------------------------------------
// k2: main fused pass. 512 blocks (8 dgrp x 64 utile) x 256. LANE = BATCH.
// Prologue: fold part1 -> LN2 stats (sc[64]). Main: loop 16 d x 8 u per wave,
// 8 p-accumulators + q,q2 in registers, scalar weight loads, no in-loop LDS.
// Epilogue: wave-fold via LDS, plain stores pp8 / qp.
// ---------------------------------------------------------------------------
__global__ void __launch_bounds__(256) k2(
    const float* __restrict__ w1, const float* __restrict__ b1,
    const float* __restrict__ g1, const float* __restrict__ be1,
    const float* __restrict__ w21, const float* __restrict__ w22,
    const float* __restrict__ b21, const float* __restrict__ b22,
    const float* __restrict__ g2, const float* __restrict__ be2,
    const float* __restrict__ w3, const float* __restrict__ b3,
    const float* __restrict__ g3,
    const float* __restrict__ xnT, const float* __restrict__ rs1a,
    const float* __restrict__ mm1a, const float* __restrict__ part1,
    float* __restrict__ pp8, float* __restrict__ qp) {
    int blk = blockIdx.x, tid = threadIdx.x;
    int utile = blk & 63, dgrp = blk >> 6;
    int u0 = utile * 8;
    int lane = tid & 63;
    int wv = __builtin_amdgcn_readfirstlane(tid >> 6);
    __shared__ float4 sc[64];
    __shared__ float tmp2[2][128];
    __shared__ float pacc[4][8][64];
    __shared__ float qacc[4][64][2];
    // prologue: fold part1 (slot s over 512 k1-blocks, split 2 ways)
    {
        int s = tid & 127, half = tid >> 7;
        float acc = 0;
        const float* p = part1 + half * 256 * 128 + s;
#pragma unroll 8
        for (int b = 0; b < 256; ++b) acc += p[b * 128];
        tmp2[half][s] = acc;
    }
    __syncthreads();
    if (tid < 64) {
        float ssum  = tmp2[0][tid] + tmp2[1][tid];
        float s2sum = tmp2[0][64 + tid] + tmp2[1][64 + tid];
        float mmv = ssum * INV_N1;
        float var = s2sum * INV_N1 - mmv * mmv;
        float r2 = rsqrtf(var + EPS);
        sc[tid] = make_float4(rs1a[tid], mm1a[tid], r2, mmv * r2);
    }
    __syncthreads();
    float4 s4 = sc[lane];   // rs1, m1*rs1, rs2, m2*rs2  (per-batch = per-lane)
    float pa[8];
#pragma unroll
    for (int ut = 0; ut < 8; ++ut) pa[ut] = 0.f;
    float q = 0.f, q2 = 0.f;
    for (int dt = 0; dt < 16; ++dt) {
        int d = dgrp * 64 + wv * 16 + dt;
        float xd = xnT[d * 64 + lane];
#pragma unroll
        for (int ut = 0; ut < 8; ++ut) {
            int idx = d * 512 + u0 + ut;
            float2 W1 = ((const float2*)w1)[idx], B1 = ((const float2*)b1)[idx];
            float2 G1 = ((const float2*)g1)[idx], E1 = ((const float2*)be1)[idx];
            float2 A  = ((const float2*)w21)[idx], C = ((const float2*)w22)[idx];
            float2 G2 = ((const float2*)g2)[idx], E2 = ((const float2*)be2)[idx];
            float2 W3 = ((const float2*)w3)[idx];
            float Ba = b21[idx], Bc = b22[idx], B3 = b3[idx], G3v = g3[idx];
            float t0 = fmaf(xd, W1.x, B1.x), t1 = fmaf(xd, W1.y, B1.y);
            float z0 = fmaf(t0, s4.x, -s4.y), z1 = fmaf(t1, s4.x, -s4.y);
            float y0 = fmaf(z0, G1.x, E1.x), y1 = fmaf(z1, G1.y, E1.y);
            float l0 = lrelu(y0), l1 = lrelu(y1);
            float c0 = fmaf(l0, A.x, fmaf(l1, A.y, Ba));
            float c1 = fmaf(l0, C.x, fmaf(l1, C.y, Bc));
            float z20 = fmaf(c0, s4.z, -s4.w), z21 = fmaf(c1, s4.z, -s4.w);
            float y20 = fmaf(z20, G2.x, E2.x), y21 = fmaf(z21, G2.y, E2.y);
            float m0 = lrelu(y20), m1v = lrelu(y21);
            float l3 = fmaf(m0, W3.x, fmaf(m1v, W3.y, B3));
            pa[ut] = fmaf(l3, G3v, pa[ut]);
            q += l3;
            q2 = fmaf(l3, l3, q2);
        }
    }
#pragma unroll
    for (int ut = 0; ut < 8; ++ut) pacc[wv][ut][lane] = pa[ut];
    qacc[wv][lane][0] = q;
    qacc[wv][lane][1] = q2;
    __syncthreads();
    // p fold: 512 outputs (b, ut)
#pragma unroll
    for (int r = 0; r < 2; ++r) {
        int idx = r * 256 + tid;
        int b = idx >> 3, ut = idx & 7;
        float s = pacc[0][ut][b] + pacc[1][ut][b] + pacc[2][ut][b] + pacc[3][ut][b];
        pp8[(dgrp * 64 + b) * 512 + u0 + ut] = s;
    }
    // q/q2 fold: per-(block, b) scalars; layout qp[(k*64+b)*512 + blk]
    if (tid < 128) {
        int k = tid >> 6, b = tid & 63;
        float s = qacc[0][b][k] + qacc[1][b][k] + qacc[2][b][k] + qacc[3][b][k];
        qp[(k * 64 + b) * 512 + blk] = s;
    }
}

// ---------------------------------------------------------------------------
// k3: 64 blocks x 512. LN3 stats from qp (contiguous per-b rows), fold pp8
// over 8 dgrps, finalize output.
// ---------------------------------------------------------------------------
__global__ void __launch_bounds__(512) k3(
    const float* __restrict__ pp8, const float* __restrict__ qp,
    const float* __restrict__ G3s, const float* __restrict__ Be3s,
    const float* __restrict__ Xs, const float* __restrict__ bias,
    float* __restrict__ out) {
    int b = blockIdx.x, u = threadIdx.x;
    float qk  = qp[(0 * 64 + b) * 512 + u];   // u doubles as blk index
    float qk2 = qp[(1 * 64 + b) * 512 + u];
    __shared__ float red[8][2];
    __shared__ float bc2[2];
    float sq = waveAllSum(qk), sq2 = waveAllSum(qk2);
    int wave = u >> 6, lane = u & 63;
    if (lane == 0) { red[wave][0] = sq; red[wave][1] = sq2; }
    __syncthreads();
    if (u == 0) {
        float a = 0, c = 0;
        for (int w = 0; w < 8; ++w) { a += red[w][0]; c += red[w][1]; }
        float m3 = a * INV_N3;
        float e3 = c * INV_N3;
        bc2[0] = m3; bc2[1] = rsqrtf(e3 - m3 * m3 + EPS);
    }
    __syncthreads();
    float p = 0;
#pragma unroll
    for (int dgrp = 0; dgrp < 8; ++dgrp)
        p += pp8[(dgrp * 64 + b) * 512 + u];
    float m3 = bc2[0], rs3 = bc2[1];
    float val = rs3 * (p - m3 * G3s[u]) + Be3s[u] + Xs[b] + bias[u];
    out[b * 512 + u] = lrelu(val);
}

extern "C" void kernel_launch(void* const* d_in, const int* in_sizes, int n_in,
                              void* d_out, int out_size, void* d_ws, size_t ws_size,
                              hipStream_t stream) {
    const float* x   = (const float*)d_in[0];
    const float* w1  = (const float*)d_in[1];
    const float* b1  = (const float*)d_in[2];
    const float* w21 = (const float*)d_in[3];
    const float* w22 = (const float*)d_in[4];
    const float* b21 = (const float*)d_in[5];
    const float* b22 = (const float*)d_in[6];
    const float* w3  = (const float*)d_in[7];
    const float* b3  = (const float*)d_in[8];
    const float* bias= (const float*)d_in[9];
    const float* g0  = (const float*)d_in[10];
    const float* be0 = (const float*)d_in[11];
    const float* g1  = (const float*)d_in[12];
    const float* be1 = (const float*)d_in[13];
    const float* g2  = (const float*)d_in[14];
    const float* be2 = (const float*)d_in[15];
    const float* g3  = (const float*)d_in[16];
    const float* be3 = (const float*)d_in[17];
    float* out = (float*)d_out;
    char* ws = (char*)d_ws;

    float*  xn    = (float*)(ws);              // 131072 [B][D]
    float*  xnT   = (float*)(ws + 131072);     // 131072 [D][B]
    float4* S4    = (float4*)(ws + 262144);    // 8192   [D]
    float*  Sb2   = (float*)(ws + 270336);     // 2048
    float*  rs1a  = (float*)(ws + 272384);     // 256
    float*  mm1a  = (float*)(ws + 272640);     // 256
    float*  Xs    = (float*)(ws + 272896);     // 256
    float*  G3s   = (float*)(ws + 273152);     // 2048
    float*  Be3s  = (float*)(ws + 275200);     // 2048
    float*  Gp    = (float*)(ws + 277248);     // 131072 [64][512]
    float*  Bp    = (float*)(ws + 408320);     // 131072
    float*  part1 = (float*)(ws + 539392);     // 262144 [512][128]
    float*  qp    = (float*)(ws + 801536);     // 262144 [128][512]
    float*  pp8   = (float*)(ws + 1063680);    // 1048576 [8*64][512]

    hipLaunchKernelGGL(kA, dim3(640), dim3(256), 0, stream,
                       w1, b1, g3, be3, x, g0, be0,
                       S4, Sb2, Gp, Bp, xn, xnT, Xs);
    hipLaunchKernelGGL(kB, dim3(66), dim3(256), 0, stream,
                       xn, S4, Sb2, Gp, Bp, rs1a, mm1a, G3s, Be3s);
    hipLaunchKernelGGL(k1, dim3(512), dim3(256), 0, stream,
                       w1, b1, g1, be1, w21, w22, b21, b22,
                       xnT, rs1a, mm1a, part1);
    hipLaunchKernelGGL(k2, dim3(512), dim3(256), 0, stream,
                       w1, b1, g1, be1, w21, w22, b21, b22, g2, be2, w3, b3, g3,
                       xnT, rs1a, mm1a, part1, pp8, qp);
    hipLaunchKernelGGL(k3, dim3(64), dim3(512), 0, stream,
                       pp8, qp, G3s, Be3s, Xs, bias, out);
}